// Round 8
// baseline (54.782 us; speedup 1.0000x reference)
//
#include <hip/hip_runtime.h>

#define L_   4096
#define LIM0 4093   // L-3 (tp positions)
#define LIM1 4092   // L-4 (pp positions)

typedef short s16x8 __attribute__((ext_vector_type(8)));
typedef float f32x4 __attribute__((ext_vector_type(4)));

__device__ __forceinline__ unsigned short f2bf(float f) {
    union { float f; unsigned int u; } v; v.f = f;
    unsigned int r = v.u + 0x7FFFu + ((v.u >> 16) & 1u);  // RNE
    return (unsigned short)(r >> 16);
}

__device__ __forceinline__ unsigned int cvt_pk_bf16(float lo, float hi) {
    unsigned int r;
    asm("v_cvt_pk_bf16_f32 %0, %1, %2" : "=v"(r) : "v"(lo), "v"(hi));
    return r;
}

struct F3 { float x, y, z; };
__device__ __forceinline__ F3 ld3(const float* p) { return F3{p[0], p[1], p[2]}; }
__device__ __forceinline__ F3 sub3(F3 a, F3 b) { return F3{a.x-b.x, a.y-b.y, a.z-b.z}; }
__device__ __forceinline__ F3 cross3(F3 a, F3 b) {
    return F3{a.y*b.z - a.z*b.y, a.z*b.x - a.x*b.z, a.x*b.y - a.y*b.x};
}
__device__ __forceinline__ float dot3(F3 a, F3 b) { return a.x*b.x + a.y*b.y + a.z*b.z; }

__device__ __forceinline__ void torsion(F3 a, F3 b, F3 c, F3 d, float& sn, float& cs) {
    F3 v1 = sub3(b, a), v2 = sub3(c, b), v3 = sub3(d, c);
    F3 n1 = cross3(v1, v2), n2 = cross3(v2, v3);
    float x = dot3(n1, n2);
    F3 m = cross3(n1, n2);
    float bn = sqrtf(dot3(v2, v2)) + 1e-8f;
    float y = dot3(m, v2) / bn;
    float inv = rsqrtf(x*x + y*y + 1e-30f);
    sn = y * inv; cs = x * inv;
}

// scalar swizzled LDS store: tile [64][256B], 16B blocks XOR'd by row&7
__device__ __forceinline__ void xstore(unsigned short* S, int rr, int c, unsigned short v) {
    S[rr*128 + (((c >> 3) ^ (rr & 7)) << 3) + (c & 7)] = v;
}

// ---- pre-kernel: per-position angle features + bf16 emb table, no divergence ----
__global__ __launch_bounds__(256) void ss_feat(const float* __restrict__ R,
                                               uint2* __restrict__ feat,
                                               const float* __restrict__ emb,
                                               uint4* __restrict__ embbf) {
    if (blockIdx.x == 0 && blockIdx.y == 0 && threadIdx.x < 40) {
        const float* ep = emb + (threadIdx.x >> 1) * 16 + (threadIdx.x & 1) * 8;
        embbf[threadIdx.x] = make_uint4(cvt_pk_bf16(ep[0], ep[1]), cvt_pk_bf16(ep[2], ep[3]),
                                        cvt_pk_bf16(ep[4], ep[5]), cvt_pk_bf16(ep[6], ep[7]));
    }
    const int p = blockIdx.x * 256 + threadIdx.x;
    const int b = blockIdx.y;
    if (p >= LIM0) return;
    const float* Rp = R + ((size_t)(b * L_ + p)) * 3;
    F3 p0 = ld3(Rp), p1 = ld3(Rp + 3), p2 = ld3(Rp + 6), p3 = ld3(Rp + 9);
    F3 u1 = sub3(p0, p1), u2 = sub3(p2, p1);
    F3 cr = cross3(u1, u2);
    float d = dot3(u1, u2);
    float ct = d * rsqrtf(d * d + dot3(cr, cr) + 1e-30f);   // cos(theta at p+1)
    float sp, cp; torsion(p0, p1, p2, p3, sp, cp);
    feat[(size_t)b * L_ + p] = make_uint2(cvt_pk_bf16(ct, 1.0f), cvt_pk_bf16(sp, cp));
}

__global__ __launch_bounds__(256) void ss_mlp(
    const int* __restrict__ seq, const uint2* __restrict__ feat,
    const uint4* __restrict__ embbf,
    const float* __restrict__ tpW1, const float* __restrict__ tpb1,
    const float* __restrict__ tpW2, const float* __restrict__ tpb2,
    const float* __restrict__ ppW1, const float* __restrict__ ppb1,
    const float* __restrict__ ppW2, const float* __restrict__ ppb2,
    float* __restrict__ ws) {

    __shared__ __align__(16) unsigned short Xs[64*128];   // [pos][k]: 0..63 ctx, 64..67 feat, 68 one
    __shared__ __align__(16) unsigned short H1s[64*128];  // [pos][hidden]

    const int b = blockIdx.y, mode = blockIdx.z, bx = blockIdx.x;
    const int lim  = mode ? LIM1 : LIM0;
    const float* W1  = mode ? ppW1 : tpW1;
    const float* Bi1 = mode ? ppb1 : tpb1;
    const float* W2  = mode ? ppW2 : tpW2;
    const float* Bi2 = mode ? ppb2 : tpb2;

    const int t = threadIdx.x;
    const int w = t >> 6, l = t & 63, g = l >> 4, ln = l & 15;
    const int lw = ln & 7;
    const int r = t >> 2, sub = t & 3;
    const int rw = r & 7;
    const size_t bL = (size_t)b * L_;

    // --- prologue stage A: seq/feat for tile0 and tile1 (in flight under weight setup) ---
    int aa0, aa_nxt; uint2 fv0 = {}, fv0b = {}, fvn = {}, fvnb = {};
    {
        const int p0 = min(bx * 64 + r, lim - 1);
        aa0 = seq[bL + p0 + sub];
        const int p1 = min(bx * 64 + 512 + r, lim - 1);
        aa_nxt = seq[bL + p1 + sub];
        if (sub == 0) {
            fv0 = feat[bL + p0];
            fvn = feat[bL + p1];
            if (mode) { fv0b = feat[bL + p0 + 1]; fvnb = feat[bL + p1 + 1]; }
        }
    }

    // zero X tile (pad cols stay zero forever)
    for (int i = t; i < 1024; i += 256) ((uint4*)Xs)[i] = make_uint4(0u, 0u, 0u, 0u);

    // A-operand weight fragments (A1 = W1^T permuted, bias1 folded via 1.0 column; A2 = W2^T)
    s16x8 a1f[2][3]; s16x8 a2f[2][4];
    float bb2[2][4];
    #pragma unroll
    for (int mt = 0; mt < 2; mt++) {
        const int hc = w*32 + mt*16 + ln;
        #pragma unroll
        for (int kk = 0; kk < 3; kk++)
            #pragma unroll
            for (int j = 0; j < 8; j++) {
                const int c = kk*32 + g*8 + j;
                int kp;
                if (mode) kp = (c < 64) ? c + 4 : ((c < 68) ? c - 64 : ((c == 68) ? -2 : -1));
                else      kp = (c < 64) ? c + 3 : ((c == 64) ? 0 : ((c == 65) ? -2 :
                               ((c == 66) ? 1 : ((c == 67) ? 2 : -1))));
                float wv = (kp == -1) ? 0.f : ((kp == -2) ? Bi1[hc] : W1[kp*128 + hc]);
                a1f[mt][kk][j] = (short)f2bf(wv);
            }
        #pragma unroll
        for (int kk = 0; kk < 4; kk++)
            #pragma unroll
            for (int j = 0; j < 8; j++)
                a2f[mt][kk][j] = (short)f2bf(W2[(kk*32 + g*8 + j)*128 + hc]);
        #pragma unroll
        for (int i = 0; i < 4; i++) bb2[mt][i] = Bi2[w*32 + mt*16 + g*4 + i];
    }

    // --- prologue stage B: emb vectors for tile0 (aa0 long arrived) ---
    uint4 e0_ = embbf[aa0*2], e1_ = embbf[aa0*2 + 1];

    __syncthreads();   // zeroed Xs visible

    // stage tile0 into Xs
    {
        *(uint4*)(Xs + r*128 + (((sub*2    ) ^ rw) << 3)) = e0_;
        *(uint4*)(Xs + r*128 + (((sub*2 + 1) ^ rw) << 3)) = e1_;
        if (sub == 0) {
            uint2 u = mode ? make_uint2(fv0.y, fv0b.y) : fv0;
            *(uint2*)(Xs + r*128 + ((8 ^ rw) << 3)) = u;   // cols 64..67
        }
    }
    if (t < 64) xstore(Xs, t, 68, (unsigned short)0x3F80);  // bias-one col
    __syncthreads();

    float s[2][4] = {{0.f,0.f,0.f,0.f},{0.f,0.f,0.f,0.f}};

    for (int it = 0; it < 8; it++) {
        const int pos0 = (bx + it*8) << 6;

        // emb gather for NEXT tile (aa_nxt loaded one iter ago); seq/feat for tile+2
        uint4 e0n, e1n;
        if (it < 7) { e0n = embbf[aa_nxt*2]; e1n = embbf[aa_nxt*2 + 1]; }
        int aa2; uint2 fv2 = {}, fv2b = {};
        if (it < 6) {
            const int p2 = min((bx + (it+2)*8)*64 + r, lim - 1);
            aa2 = seq[bL + p2 + sub];
            if (sub == 0) {
                fv2 = feat[bL + p2];
                if (mode) fv2b = feat[bL + p2 + 1];
            }
        }

        // ---- GEMM1: D1 = W1^T · X^T ; h1 = relu(D1) (bias folded) -> H1s[pos][hidden] ----
        #pragma unroll
        for (int pt = 0; pt < 4; pt++) {
            const int row = pt*16 + ln;
            const unsigned short* base = Xs + row*128;
            f32x4 c0 = {0.f,0.f,0.f,0.f}, c1 = {0.f,0.f,0.f,0.f};
            #pragma unroll
            for (int kk = 0; kk < 3; kk++) {
                s16x8 bf = *(const s16x8*)(base + (((kk*4 + g) ^ lw) << 3));
                c0 = __builtin_amdgcn_mfma_f32_16x16x32_bf16(a1f[0][kk], bf, c0, 0, 0, 0);
                c1 = __builtin_amdgcn_mfma_f32_16x16x32_bf16(a1f[1][kk], bf, c1, 0, 0, 0);
            }
            unsigned short* hb = H1s + row*128;
            {
                uint2 u;
                u.x = cvt_pk_bf16(fmaxf(c0[0], 0.f), fmaxf(c0[1], 0.f));
                u.y = cvt_pk_bf16(fmaxf(c0[2], 0.f), fmaxf(c0[3], 0.f));
                *(uint2*)(hb + ((((w*4) + (g>>1)) ^ lw) << 3) + (g&1)*4) = u;
            }
            {
                uint2 u;
                u.x = cvt_pk_bf16(fmaxf(c1[0], 0.f), fmaxf(c1[1], 0.f));
                u.y = cvt_pk_bf16(fmaxf(c1[2], 0.f), fmaxf(c1[3], 0.f));
                *(uint2*)(hb + ((((w*4 + 2) + (g>>1)) ^ lw) << 3) + (g&1)*4) = u;
            }
        }
        __syncthreads();   // B1: Xs reads + H1s writes complete

        // write NEXT tile's Xs (concurrent with GEMM2's H1s reads)
        if (it < 7) {
            *(uint4*)(Xs + r*128 + (((sub*2    ) ^ rw) << 3)) = e0n;
            *(uint4*)(Xs + r*128 + (((sub*2 + 1) ^ rw) << 3)) = e1n;
            if (sub == 0) {
                uint2 u = mode ? make_uint2(fvn.y, fvnb.y) : fvn;
                *(uint2*)(Xs + r*128 + ((8 ^ rw) << 3)) = u;
            }
        }

        // ---- GEMM2: D2 = W2^T · H1^T ; masked colsum of relu(D2 + b2) ----
        #pragma unroll
        for (int pt = 0; pt < 4; pt++) {
            const int row = pt*16 + ln;
            const unsigned short* base = H1s + row*128;
            f32x4 d0 = {0.f,0.f,0.f,0.f}, d1 = {0.f,0.f,0.f,0.f};
            #pragma unroll
            for (int kk = 0; kk < 4; kk++) {
                s16x8 bf = *(const s16x8*)(base + (((kk*4 + g) ^ lw) << 3));
                d0 = __builtin_amdgcn_mfma_f32_16x16x32_bf16(a2f[0][kk], bf, d0, 0, 0, 0);
                d1 = __builtin_amdgcn_mfma_f32_16x16x32_bf16(a2f[1][kk], bf, d1, 0, 0, 0);
            }
            if (pos0 + row < lim) {
                #pragma unroll
                for (int i = 0; i < 4; i++) {
                    s[0][i] += fmaxf(d0[i] + bb2[0][i], 0.f);
                    s[1][i] += fmaxf(d1[i] + bb2[1][i], 0.f);
                }
            }
        }
        __syncthreads();   // B2: H1s reads + next-Xs writes complete

        if (it < 6) { aa_nxt = aa2; fvn = fv2; fvnb = fv2b; }
    }

    // reduce across the 16 lanes sharing each hidden index, one atomic per value
    #pragma unroll
    for (int mt = 0; mt < 2; mt++)
        #pragma unroll
        for (int i = 0; i < 4; i++) {
            float v = s[mt][i];
            v += __shfl_xor(v, 1, 64); v += __shfl_xor(v, 2, 64);
            v += __shfl_xor(v, 4, 64); v += __shfl_xor(v, 8, 64);
            if (ln == 0)
                atomicAdd(ws + ((b*2 + mode) << 7) + w*32 + mt*16 + g*4 + i, v);
        }
}

__global__ void ss_finish(const float* __restrict__ ws,
                          const float* __restrict__ tpW3, const float* __restrict__ tpb3,
                          const float* __restrict__ ppW3, const float* __restrict__ ppb3,
                          float* __restrict__ out) {
    const int b = blockIdx.x, t = threadIdx.x;   // 128 threads
    float v = ws[(b*2 + 0)*128 + t] * tpW3[t] + ws[(b*2 + 1)*128 + t] * ppW3[t];
    #pragma unroll
    for (int off = 1; off < 64; off <<= 1) v += __shfl_xor(v, off, 64);
    __shared__ float ps[2];
    if ((t & 63) == 0) ps[t >> 6] = v;
    __syncthreads();
    if (t == 0) out[b] = ps[0] + ps[1] + 4093.f * tpb3[0] + 4092.f * ppb3[0];
}

extern "C" void kernel_launch(void* const* d_in, const int* in_sizes, int n_in,
                              void* d_out, int out_size, void* d_ws, size_t ws_size,
                              hipStream_t stream) {
    (void)in_sizes; (void)n_in; (void)out_size; (void)ws_size;
    const float* R    = (const float*)d_in[0];
    const int*   seq  = (const int*)d_in[1];
    const float* emb  = (const float*)d_in[2];
    const float* tpW1 = (const float*)d_in[3];
    const float* tpb1 = (const float*)d_in[4];
    const float* tpW2 = (const float*)d_in[5];
    const float* tpb2 = (const float*)d_in[6];
    const float* tpW3 = (const float*)d_in[7];
    const float* tpb3 = (const float*)d_in[8];
    const float* ppW1 = (const float*)d_in[9];
    const float* ppb1 = (const float*)d_in[10];
    const float* ppW2 = (const float*)d_in[11];
    const float* ppb2 = (const float*)d_in[12];
    const float* ppW3 = (const float*)d_in[13];
    const float* ppb3 = (const float*)d_in[14];
    float* ws    = (float*)d_ws;                                  // [0, 64KB): column sums
    uint2* feat  = (uint2*)((char*)d_ws + 65536);                 // [64KB, 64KB+2MB): features
    uint4* embbf = (uint4*)((char*)d_ws + 65536 + 2097152);       // 640 B: bf16 emb table

    hipMemsetAsync(ws, 0, 64*2*128*sizeof(float), stream);
    ss_feat<<<dim3(16, 64), 256, 0, stream>>>(R, feat, emb, embbf);
    ss_mlp<<<dim3(8, 64, 2), 256, 0, stream>>>(seq, feat, embbf,
                                               tpW1, tpb1, tpW2, tpb2,
                                               ppW1, ppb1, ppW2, ppb2, ws);
    ss_finish<<<64, 128, 0, stream>>>(ws, tpW3, tpb3, ppW3, ppb3, (float*)d_out);
}

// Round 9
// 52.338 us; speedup vs baseline: 1.0467x; 1.0467x over previous
//
#include <hip/hip_runtime.h>

#define L_   4096
#define LIM0 4093   // L-3 (tp positions)
#define LIM1 4092   // L-4 (pp positions)

typedef short s16x8 __attribute__((ext_vector_type(8)));
typedef float f32x4 __attribute__((ext_vector_type(4)));

__device__ __forceinline__ unsigned short f2bf(float f) {
    union { float f; unsigned int u; } v; v.f = f;
    unsigned int r = v.u + 0x7FFFu + ((v.u >> 16) & 1u);  // RNE
    return (unsigned short)(r >> 16);
}

__device__ __forceinline__ unsigned int cvt_pk_bf16(float lo, float hi) {
    unsigned int r;
    asm("v_cvt_pk_bf16_f32 %0, %1, %2" : "=v"(r) : "v"(lo), "v"(hi));
    return r;
}

struct F3 { float x, y, z; };
__device__ __forceinline__ F3 ld3(const float* p) { return F3{p[0], p[1], p[2]}; }
__device__ __forceinline__ F3 sub3(F3 a, F3 b) { return F3{a.x-b.x, a.y-b.y, a.z-b.z}; }
__device__ __forceinline__ F3 cross3(F3 a, F3 b) {
    return F3{a.y*b.z - a.z*b.y, a.z*b.x - a.x*b.z, a.x*b.y - a.y*b.x};
}
__device__ __forceinline__ float dot3(F3 a, F3 b) { return a.x*b.x + a.y*b.y + a.z*b.z; }

__device__ __forceinline__ void torsion(F3 a, F3 b, F3 c, F3 d, float& sn, float& cs) {
    F3 v1 = sub3(b, a), v2 = sub3(c, b), v3 = sub3(d, c);
    F3 n1 = cross3(v1, v2), n2 = cross3(v2, v3);
    float x = dot3(n1, n2);
    F3 m = cross3(n1, n2);
    float bn = sqrtf(dot3(v2, v2)) + 1e-8f;
    float y = dot3(m, v2) / bn;
    float inv = rsqrtf(x*x + y*y + 1e-30f);
    sn = y * inv; cs = x * inv;
}

#define MFMA16 __builtin_amdgcn_mfma_f32_16x16x32_bf16

// Block = 256 threads (4 waves, hidden-split 32 each); covers 256 contiguous positions
// (4 iters x 64). GEMM1 B-frags gathered directly from LDS emb table + feats array
// (X tile never materialized). Only the H1 round-trip needs barriers (2/iter).
__global__ __launch_bounds__(256) void ss_mlp(
    const float* __restrict__ R, const int* __restrict__ seq, const float* __restrict__ emb,
    const float* __restrict__ tpW1, const float* __restrict__ tpb1,
    const float* __restrict__ tpW2, const float* __restrict__ tpb2,
    const float* __restrict__ ppW1, const float* __restrict__ ppb1,
    const float* __restrict__ ppW2, const float* __restrict__ ppb2,
    float* __restrict__ wsp) {

    __shared__ __align__(16) unsigned short H1s[64*128];  // [pos][hidden], XOR-swizzled
    __shared__ __align__(16) uint4 embs4[40];             // bf16 emb: [aa][half]
    __shared__ unsigned int feats[520];                   // packed per-pos angle features

    const int b = blockIdx.y, mode = blockIdx.z, bx = blockIdx.x;
    const int lim = mode ? LIM1 : LIM0;
    const float* W1  = mode ? ppW1 : tpW1;
    const float* Bi1 = mode ? ppb1 : tpb1;
    const float* W2  = mode ? ppW2 : tpW2;
    const float* Bi2 = mode ? ppb2 : tpb2;

    const int t = threadIdx.x;
    const int w = t >> 6, l = t & 63, g = l >> 4, ln = l & 15;
    const int lw = ln & 7;
    const size_t bL = (size_t)b * L_;
    const int base = bx * 256;
    const int* seqb = seq + bL;

    // ---- iter-0 seq prefetch: residue index per (pt,kk) ----
    int aa_c[8];
    #pragma unroll
    for (int pt = 0; pt < 4; pt++)
        #pragma unroll
        for (int kk = 0; kk < 2; kk++)
            aa_c[pt*2+kk] = seqb[min(base + pt*16 + ln + kk*2 + (g>>1), L_-1)];

    // ---- per-position features: one torsion per thread, no divergence ----
    {
        const int pc = min(base + t, lim - 1);
        const float* Rp = R + ((size_t)(bL + pc)) * 3;
        F3 p0 = ld3(Rp), p1 = ld3(Rp+3), p2 = ld3(Rp+6), p3 = ld3(Rp+9);
        float sp, cp; torsion(p0, p1, p2, p3, sp, cp);
        if (mode == 0) {
            F3 u1 = sub3(p0, p1), u2 = sub3(p2, p1);
            F3 cr = cross3(u1, u2);
            float d = dot3(u1, u2);
            float ct = d * rsqrtf(d*d + dot3(cr, cr) + 1e-30f);
            feats[2*t]   = cvt_pk_bf16(ct, sp);     // k-slots j=0,1: cos_theta, sin_phi
            feats[2*t+1] = cvt_pk_bf16(cp, 1.0f);   // j=2,3: cos_phi, bias-one
        } else {
            feats[t] = cvt_pk_bf16(sp, cp);         // j=0,1 of pos i (j=2,3 from pos i+1)
            if (t == 0) {                            // boundary: feats for pos base+256
                const int pc2 = min(base + 256, lim - 1);
                const float* R2 = R + ((size_t)(bL + pc2)) * 3;
                F3 q0 = ld3(R2), q1 = ld3(R2+3), q2 = ld3(R2+6), q3 = ld3(R2+9);
                float s2, c2; torsion(q0, q1, q2, q3, s2, c2);
                feats[256] = cvt_pk_bf16(s2, c2);
            }
        }
    }

    // ---- bf16 emb table ----
    if (t < 40) {
        const float* ep = emb + (t >> 1) * 16 + (t & 1) * 8;
        embs4[t] = make_uint4(cvt_pk_bf16(ep[0], ep[1]), cvt_pk_bf16(ep[2], ep[3]),
                              cvt_pk_bf16(ep[4], ep[5]), cvt_pk_bf16(ep[6], ep[7]));
    }

    // ---- weight A-fragments; X-col layout: 0..63 ctx, 64.. angle feats, then bias-one ----
    s16x8 a1f[2][3]; s16x8 a2f[2][4];
    float bb2[2][4];
    #pragma unroll
    for (int mt = 0; mt < 2; mt++) {
        const int hc = w*32 + mt*16 + ln;
        #pragma unroll
        for (int kk = 0; kk < 3; kk++)
            #pragma unroll
            for (int j = 0; j < 8; j++) {
                const int c = kk*32 + g*8 + j;
                int kp;
                if (mode) kp = (c < 64) ? c + 4 : ((c < 68) ? c - 64 : ((c == 68) ? -2 : -1));
                else      kp = (c < 64) ? c + 3 : ((c < 67) ? c - 64 : ((c == 67) ? -2 : -1));
                float wv = (kp == -1) ? 0.f : ((kp == -2) ? Bi1[hc] : W1[kp*128 + hc]);
                a1f[mt][kk][j] = (short)f2bf(wv);
            }
        #pragma unroll
        for (int kk = 0; kk < 4; kk++)
            #pragma unroll
            for (int j = 0; j < 8; j++)
                a2f[mt][kk][j] = (short)f2bf(W2[(kk*32 + g*8 + j)*128 + hc]);
        #pragma unroll
        for (int i = 0; i < 4; i++) bb2[mt][i] = Bi2[w*32 + mt*16 + g*4 + i];
    }

    __syncthreads();   // feats + embs4 visible

    float s[2][4] = {{0.f,0.f,0.f,0.f},{0.f,0.f,0.f,0.f}};

    #pragma unroll
    for (int it = 0; it < 4; it++) {
        const int pos0 = base + it*64;

        // seq prefetch for next iter (hidden under GEMM1+GEMM2)
        int aa_n[8];
        if (it < 3) {
            #pragma unroll
            for (int pt = 0; pt < 4; pt++)
                #pragma unroll
                for (int kk = 0; kk < 2; kk++)
                    aa_n[pt*2+kk] = seqb[min(pos0 + 64 + pt*16 + ln + kk*2 + (g>>1), L_-1)];
        }

        // ---- GEMM1: D1 = W1^T · X^T, B-frags gathered from embs4/feats ----
        #pragma unroll
        for (int pt = 0; pt < 4; pt++) {
            const int row = pt*16 + ln;
            const int fidx = it*64 + row;
            s16x8 b0 = *(const s16x8*)&embs4[aa_c[pt*2+0]*2 + (g&1)];
            s16x8 b1 = *(const s16x8*)&embs4[aa_c[pt*2+1]*2 + (g&1)];
            unsigned int f0, f1, f2c;
            if (mode) { f0 = feats[fidx]; f1 = feats[fidx+1]; f2c = 0x00003F80u; }
            else      { f0 = feats[2*fidx]; f1 = feats[2*fidx+1]; f2c = 0u; }
            const bool gz = (g == 0);
            union { unsigned int u[4]; s16x8 v; } fb;
            fb.u[0] = gz ? f0 : 0u; fb.u[1] = gz ? f1 : 0u;
            fb.u[2] = gz ? f2c : 0u; fb.u[3] = 0u;

            f32x4 c0 = {0.f,0.f,0.f,0.f}, c1 = {0.f,0.f,0.f,0.f};
            c0 = MFMA16(a1f[0][0], b0, c0, 0, 0, 0);
            c1 = MFMA16(a1f[1][0], b0, c1, 0, 0, 0);
            c0 = MFMA16(a1f[0][1], b1, c0, 0, 0, 0);
            c1 = MFMA16(a1f[1][1], b1, c1, 0, 0, 0);
            c0 = MFMA16(a1f[0][2], fb.v, c0, 0, 0, 0);
            c1 = MFMA16(a1f[1][2], fb.v, c1, 0, 0, 0);

            unsigned short* hb = H1s + row*128;
            uint2 u;
            u.x = cvt_pk_bf16(fmaxf(c0[0], 0.f), fmaxf(c0[1], 0.f));
            u.y = cvt_pk_bf16(fmaxf(c0[2], 0.f), fmaxf(c0[3], 0.f));
            *(uint2*)(hb + ((((w*4) + (g>>1)) ^ lw) << 3) + (g&1)*4) = u;
            u.x = cvt_pk_bf16(fmaxf(c1[0], 0.f), fmaxf(c1[1], 0.f));
            u.y = cvt_pk_bf16(fmaxf(c1[2], 0.f), fmaxf(c1[3], 0.f));
            *(uint2*)(hb + ((((w*4 + 2) + (g>>1)) ^ lw) << 3) + (g&1)*4) = u;
        }
        __syncthreads();   // H1s written

        // ---- GEMM2: D2 = W2^T · H1^T ; masked colsum of relu(D2 + b2) ----
        #pragma unroll
        for (int pt = 0; pt < 4; pt++) {
            const int row = pt*16 + ln;
            const unsigned short* hbase = H1s + row*128;
            f32x4 d0 = {0.f,0.f,0.f,0.f}, d1 = {0.f,0.f,0.f,0.f};
            #pragma unroll
            for (int kk = 0; kk < 4; kk++) {
                s16x8 bf = *(const s16x8*)(hbase + (((kk*4 + g) ^ lw) << 3));
                d0 = MFMA16(a2f[0][kk], bf, d0, 0, 0, 0);
                d1 = MFMA16(a2f[1][kk], bf, d1, 0, 0, 0);
            }
            if (pos0 + row < lim) {
                #pragma unroll
                for (int i = 0; i < 4; i++) {
                    s[0][i] += fmaxf(d0[i] + bb2[0][i], 0.f);
                    s[1][i] += fmaxf(d1[i] + bb2[1][i], 0.f);
                }
            }
        }
        __syncthreads();   // H1s reads done (buffer reused next iter)

        if (it < 3) {
            #pragma unroll
            for (int j = 0; j < 8; j++) aa_c[j] = aa_n[j];
        }
    }

    // reduce over the 16 lanes of each g-group; one float4 store per (wave, mt)
    #pragma unroll
    for (int mt = 0; mt < 2; mt++)
        #pragma unroll
        for (int i = 0; i < 4; i++) {
            float v = s[mt][i];
            v += __shfl_xor(v, 1, 64); v += __shfl_xor(v, 2, 64);
            v += __shfl_xor(v, 4, 64); v += __shfl_xor(v, 8, 64);
            s[mt][i] = v;
        }
    if (ln == 0) {
        float* dst = wsp + (((size_t)(b*2 + mode)*16 + bx) << 7) + w*32;
        *(f32x4*)(dst +  0 + g*4) = f32x4{s[0][0], s[0][1], s[0][2], s[0][3]};
        *(f32x4*)(dst + 16 + g*4) = f32x4{s[1][0], s[1][1], s[1][2], s[1][3]};
    }
}

__global__ void ss_finish(const float* __restrict__ wsp,
                          const float* __restrict__ tpW3, const float* __restrict__ tpb3,
                          const float* __restrict__ ppW3, const float* __restrict__ ppb3,
                          float* __restrict__ out) {
    const int b = blockIdx.x, t = threadIdx.x;   // 128 threads
    const float* p0 = wsp + ((size_t)(b*2 + 0) * 16) * 128;
    const float* p1 = wsp + ((size_t)(b*2 + 1) * 16) * 128;
    float a0 = 0.f, a1 = 0.f;
    #pragma unroll
    for (int bx = 0; bx < 16; bx++) {
        a0 += p0[bx*128 + t];
        a1 += p1[bx*128 + t];
    }
    float v = a0 * tpW3[t] + a1 * ppW3[t];
    #pragma unroll
    for (int off = 1; off < 64; off <<= 1) v += __shfl_xor(v, off, 64);
    __shared__ float ps[2];
    if ((t & 63) == 0) ps[t >> 6] = v;
    __syncthreads();
    if (t == 0) out[b] = ps[0] + ps[1] + 4093.f * tpb3[0] + 4092.f * ppb3[0];
}

extern "C" void kernel_launch(void* const* d_in, const int* in_sizes, int n_in,
                              void* d_out, int out_size, void* d_ws, size_t ws_size,
                              hipStream_t stream) {
    (void)in_sizes; (void)n_in; (void)out_size; (void)ws_size;
    const float* R    = (const float*)d_in[0];
    const int*   seq  = (const int*)d_in[1];
    const float* emb  = (const float*)d_in[2];
    const float* tpW1 = (const float*)d_in[3];
    const float* tpb1 = (const float*)d_in[4];
    const float* tpW2 = (const float*)d_in[5];
    const float* tpb2 = (const float*)d_in[6];
    const float* tpW3 = (const float*)d_in[7];
    const float* tpb3 = (const float*)d_in[8];
    const float* ppW1 = (const float*)d_in[9];
    const float* ppb1 = (const float*)d_in[10];
    const float* ppW2 = (const float*)d_in[11];
    const float* ppb2 = (const float*)d_in[12];
    const float* ppW3 = (const float*)d_in[13];
    const float* ppb3 = (const float*)d_in[14];
    float* wsp = (float*)d_ws;   // [64][2][16][128] block partial sums, 1 MB (fully overwritten)

    ss_mlp<<<dim3(16, 64, 2), 256, 0, stream>>>(R, seq, emb,
                                                tpW1, tpb1, tpW2, tpb2,
                                                ppW1, ppb1, ppW2, ppb2, wsp);
    ss_finish<<<64, 128, 0, stream>>>(wsp, tpW3, tpb3, ppW3, ppb3, (float*)d_out);
}